// Round 16
// baseline (254.757 us; speedup 1.0000x reference)
//
#include <hip/hip_runtime.h>
#include <hip/hip_bf16.h>

#define BB 8
#define SS 2500
#define EE 128
#define FF 128
#define LL 8921

using bf8 = __attribute__((ext_vector_type(8))) short;
using bf4 = __attribute__((ext_vector_type(4))) short;
using f4  = __attribute__((ext_vector_type(4))) float;

__device__ __forceinline__ short f2bf(float f) {
  unsigned u = __builtin_bit_cast(unsigned, f);
  u += 0x7fffu + ((u >> 16) & 1u);
  return (short)(u >> 16);
}

// async global->LDS, 16B per lane; LDS dest is wave-uniform base + lane*16
__device__ __forceinline__ void gll16(const void* g, void* l) {
  __builtin_amdgcn_global_load_lds(
      (const __attribute__((address_space(1))) unsigned int*)g,
      (__attribute__((address_space(3))) unsigned int*)l, 16, 0, 0);
}

// ---------------- prep: embed gather -> bf16, wu -> bf16, conv w repack ----------------
__global__ void prep_kernel(const int* __restrict__ docs, const int* __restrict__ leaf,
                            const float* __restrict__ embed, const float* __restrict__ wu,
                            const float* __restrict__ w3, const float* __restrict__ w5,
                            const float* __restrict__ w9,
                            short* __restrict__ x_bf, short* __restrict__ wu_bf,
                            short* __restrict__ wpack) {
  const int NX = BB * SS * EE / 8;   // 320000
  const int NU = LL * FF / 8;        // 142736
  const int NW = 17 * FF * EE;       // 278528
  int tid = blockIdx.x * 256 + threadIdx.x;
  if (tid < NX) {
    int base = tid * 8;
    int bs = base >> 7, e0 = base & 127;
    int row = docs[bs];
    const float* p = embed + (row << 7) + e0;
    bf8 o;
#pragma unroll
    for (int i = 0; i < 8; ++i) o[i] = f2bf(p[i]);
    *(bf8*)(x_bf + base) = o;
  } else if (tid < NX + NU) {
    int base = (tid - NX) * 8;
    int l = base >> 7, f0 = base & 127;
    int row = leaf[l];
    const float* p = wu + (row << 7) + f0;
    bf8 o;
#pragma unroll
    for (int i = 0; i < 8; ++i) o[i] = f2bf(p[i]);
    *(bf8*)(wu_bf + base) = o;
  } else if (tid < NX + NU + NW) {
    int i = tid - NX - NU;
    int t = i >> 14, fe = i & 16383;
    const float* w; int K, dk;
    if (t < 3)      { w = w3; K = 3; dk = t; }
    else if (t < 8) { w = w5; K = 5; dk = t - 3; }
    else            { w = w9; K = 9; dk = t - 8; }
    wpack[i] = f2bf(w[fe * K + dk]);
  }
}

// ---------------- conv: 3 kernels + tanh + max, MFMA over (e,tap) ----------------
__global__ __launch_bounds__(256, 2) void conv_kernel(
    const short* __restrict__ x_bf, const short* __restrict__ wpack,
    const float* __restrict__ cb3, const float* __restrict__ cb5, const float* __restrict__ cb9,
    short* __restrict__ wf, short* __restrict__ wfT) {
  __shared__ short xt[72][136];   // s rows (halo 4), e cols; 272B stride
  __shared__ short wt[128][136];  // f rows, e cols
  int b = blockIdx.x;             // b fastest -> XCD-local x_bf/wpack
  int s0 = blockIdx.y * 64;
  int tid = threadIdx.x, wid = tid >> 6, lane = tid & 63, g = lane >> 4, c = lane & 15;

  for (int i = tid; i < 72 * 16; i += 256) {
    int r = i >> 4, c8 = (i & 15) << 3, s = s0 + r - 4;
    bf8 v = {0, 0, 0, 0, 0, 0, 0, 0};
    if (s >= 0 && s < SS) v = *(const bf8*)(x_bf + ((b * SS + s) << 7) + c8);
    *(bf8*)&xt[r][c8] = v;
  }

  bf8 wpre[8];
#pragma unroll
  for (int k = 0; k < 8; ++k) {
    int i = tid + (k << 8); int r = i >> 4, c8 = (i & 15) << 3;
    wpre[k] = *(const bf8*)(wpack + (r << 7) + c8);
  }

  float wfm[8][4];
#pragma unroll
  for (int j = 0; j < 8; ++j)
#pragma unroll
    for (int i = 0; i < 4; ++i) wfm[j][i] = -1e30f;

  int tap = 0;
  for (int kid = 0; kid < 3; ++kid) {
    const float* cb = (kid == 0) ? cb3 : (kid == 1) ? cb5 : cb9;
    const int K = (kid == 0) ? 3 : (kid == 1) ? 5 : 9;
    const int pad = K >> 1;
    f4 acc[8];
#pragma unroll
    for (int j = 0; j < 8; ++j) {
      float bvj = cb[j * 16 + c];
      acc[j] = (f4){bvj, bvj, bvj, bvj};
    }
    for (int dk = 0; dk < K; ++dk, ++tap) {
      __syncthreads();
#pragma unroll
      for (int k = 0; k < 8; ++k) {
        int i = tid + (k << 8); int r = i >> 4, c8 = (i & 15) << 3;
        *(bf8*)&wt[r][c8] = wpre[k];
      }
      if (tap < 16) {
#pragma unroll
        for (int k = 0; k < 8; ++k) {
          int i = tid + (k << 8); int r = i >> 4, c8 = (i & 15) << 3;
          wpre[k] = *(const bf8*)(wpack + (tap + 1) * 16384 + (r << 7) + c8);
        }
      }
      __syncthreads();
      int xr = wid * 16 + c + dk - pad + 4;
      __builtin_amdgcn_s_setprio(1);
#pragma unroll
      for (int ks = 0; ks < 4; ++ks) {
        bf8 a = *(const bf8*)&xt[xr][ks * 32 + g * 8];
#pragma unroll
        for (int j = 0; j < 8; ++j) {
          bf8 bb = *(const bf8*)&wt[j * 16 + c][ks * 32 + g * 8];
          acc[j] = __builtin_amdgcn_mfma_f32_16x16x32_bf16(a, bb, acc[j], 0, 0, 0);
        }
      }
      __builtin_amdgcn_s_setprio(0);
    }
#pragma unroll
    for (int j = 0; j < 8; ++j)
#pragma unroll
      for (int i = 0; i < 4; ++i) wfm[j][i] = fmaxf(wfm[j][i], tanhf(acc[j][i]));
  }

  int sb = s0 + wid * 16 + g * 4;
#pragma unroll
  for (int j = 0; j < 8; ++j) {
    int f = j * 16 + c;
#pragma unroll
    for (int i = 0; i < 4; ++i) {
      int s = sb + i;
      if (s < SS) wf[((b * SS + s) << 7) + f] = f2bf(wfm[j][i]);
    }
    int tbase = (b * 128 + f) * SS + sb;
    if (sb + 3 < SS) {
      bf4 pk;
#pragma unroll
      for (int i = 0; i < 4; ++i) pk[i] = f2bf(wfm[j][i]);
      *(bf4*)(wfT + tbase) = pk;
    } else {
#pragma unroll
      for (int i = 0; i < 4; ++i)
        if (sb + i < SS) wfT[tbase + i] = f2bf(wfm[j][i]);
    }
  }
}

// ---------------- flash attention + fused y, SWAPPED-QK (P never touches LDS) --------
// mfma(K,Q): lane (c,g) holds P[s=st*16+4g+i][l=strip+c] — exactly the B-frag that
// v_mfma_f32_16x16x16_bf16 PV needs (k=4g..4g+3 per lane). Deleted vs R15: pt buffer
// (17.4KB LDS), 32 pt writes + 16 pa reads + lgkm drain, all rowsum16 DPP chains
// (denominator is lane-local; one shfl pair per block in epilogue). O accumulates as
// O^T[f][l]; epilogue writes ctx as aligned f4 (4 g-lanes complete each 64B line).
// Staging/barriers/q-loads byte-identical to R15. LDS 32.8KB; (256,3) cap, VGPR <= 84.
__global__ __launch_bounds__(256, 3) void attn_kernel(
    const short* __restrict__ wu_bf, const short* __restrict__ wf, const short* __restrict__ wfT,
    const float* __restrict__ fw, const float* __restrict__ fb,
    float* __restrict__ y, float* __restrict__ ctx) {
  __shared__ short kt[64 * 128];   // K tile [s][f], swizzled  (16,384 B)
  __shared__ short vt[128 * 64];   // V^T tile [f][s], swizzled (16,384 B)
  int b = blockIdx.x;              // b fastest -> per-XCD K/V residency in L2
  int l0 = blockIdx.y * 128;
  int tid = threadIdx.x, wid = tid >> 6, lane = tid & 63, g = lane >> 4, c = lane & 15;

  // staging source precompute (tile-invariant): call k covers linear chunks (k*4+wid)*64+lane
  int k_row[4], k_off[4], v_off[4];
#pragma unroll
  for (int k = 0; k < 4; ++k) {
    int idx = (k * 4 + wid) * 64 + lane;
    int r = idx >> 4, ck = idx & 15;
    k_row[k] = r;
    k_off[k] = (ck ^ (r & 15)) << 3;             // shorts within wf row
    int rv = idx >> 3, cv = idx & 7;
    v_off[k] = (b * 128 + rv) * SS + ((cv ^ (rv & 7)) << 3);  // shorts into wfT (+s0 per tile)
  }
  const short* wfb = wf + b * SS * 128;

  bf8 q[2][4];  // B-operand: lane (c,g): Q[l=strip+c][e=ks*32+8g..+7] — same loads as ever
#pragma unroll
  for (int ms = 0; ms < 2; ++ms) {
    int l = l0 + wid * 32 + ms * 16 + c;
    if (l >= LL) l = LL - 1;
#pragma unroll
    for (int ks = 0; ks < 4; ++ks)
      q[ms][ks] = *(const bf8*)(wu_bf + (l << 7) + ks * 32 + g * 8);
  }

  float lst[2] = {0.f, 0.f};  // per-lane PARTIAL denominator (s ≡ 4g+i mod 16 subset)
  f4 o[2][8];                 // O^T: lane (c,g) rows f=n*16+4g+i, col l=strip+c
#pragma unroll
  for (int ms = 0; ms < 2; ++ms)
#pragma unroll
    for (int n = 0; n < 8; ++n) o[ms][n] = (f4){0.f, 0.f, 0.f, 0.f};

  for (int t = 0; t < 40; ++t) {
    int s0 = t * 64;
    bool full = (s0 + 64 <= SS);
    __syncthreads();  // all waves done reading tile t-1
    // stage K tile (rows clamped; garbage rows masked via per-element s<SS)
#pragma unroll
    for (int k = 0; k < 4; ++k) {
      int s = s0 + k_row[k];
      if (s > SS - 1) s = SS - 1;
      gll16(wfb + s * 128 + k_off[k], (char*)kt + (k * 4 + wid) * 1024);
    }
    if (full) {
#pragma unroll
      for (int k = 0; k < 4; ++k)
        gll16(wfT + v_off[k] + s0, (char*)vt + (k * 4 + wid) * 1024);
    } else {
      // tail tile: scalar masked V staging through the same swizzle
      for (int idx = tid; idx < 128 * 64; idx += 256) {
        int r = idx >> 6, sl = idx & 63, so = s0 + sl;
        short v = (so < SS) ? wfT[(b * 128 + r) * SS + so] : (short)0;
        vt[(r << 6) + (((sl >> 3) ^ (r & 7)) << 3) + (sl & 7)] = v;
      }
    }
    __syncthreads();  // barrier drain waits vmcnt(0): tile t staged

#pragma unroll
    for (int sh = 0; sh < 2; ++sh) {   // st-half: bounds live registers (sc[2][2])
      // QK^T swapped: A = K rows (st*16+c), B = Q
      f4 sc[2][2];  // [st2][ms]
#pragma unroll
      for (int st2 = 0; st2 < 2; ++st2)
#pragma unroll
        for (int ms = 0; ms < 2; ++ms) sc[st2][ms] = (f4){0.f, 0.f, 0.f, 0.f};
      __builtin_amdgcn_s_setprio(1);
#pragma unroll
      for (int ks = 0; ks < 4; ++ks) {
        int xk = (((ks << 2) | g) ^ c) << 3;
        bf8 ka[2];
#pragma unroll
        for (int st2 = 0; st2 < 2; ++st2)
          ka[st2] = *(const bf8*)&kt[(((sh * 2 + st2) * 16) + c) * 128 + xk];
#pragma unroll
        for (int st2 = 0; st2 < 2; ++st2)
#pragma unroll
          for (int ms = 0; ms < 2; ++ms)
            sc[st2][ms] = __builtin_amdgcn_mfma_f32_16x16x32_bf16(ka[st2], q[ms][ks], sc[st2][ms], 0, 0, 0);
      }
      __builtin_amdgcn_s_setprio(0);

#pragma unroll
      for (int st2 = 0; st2 < 2; ++st2) {
        int st = sh * 2 + st2;
        // softmax: fully lane-local (P[s][l=c] lives where PV wants it)
        bf4 pb[2];
#pragma unroll
        for (int ms = 0; ms < 2; ++ms) {
          f4 p;
          if (full) {
#pragma unroll
            for (int i = 0; i < 4; ++i) p[i] = __expf(sc[st2][ms][i]);
          } else {
#pragma unroll
            for (int i = 0; i < 4; ++i) {
              int s = s0 + st * 16 + (g << 2) + i;
              p[i] = (s < SS) ? __expf(sc[st2][ms][i]) : 0.0f;
            }
          }
          lst[ms] += p[0] + p[1] + p[2] + p[3];
#pragma unroll
          for (int i = 0; i < 4; ++i) pb[ms][i] = f2bf(p[i]);
        }
        // PV: A = V^T rows (n*16+c, k=s 4g..4g+3), B = P (in regs)
        __builtin_amdgcn_s_setprio(1);
#pragma unroll
        for (int n = 0; n < 8; ++n) {
          int col = st * 16 + (g << 2);
          int off = (((col >> 3) ^ (c & 7)) << 3) + (col & 7);
          bf4 vb = *(const bf4*)&vt[(n * 16 + c) * 64 + off];
#pragma unroll
          for (int ms = 0; ms < 2; ++ms)
            o[ms][n] = __builtin_amdgcn_mfma_f32_16x16x16bf16_1k(vb, pb[ms], o[ms][n], 0, 0, 0);
        }
        __builtin_amdgcn_s_setprio(0);
      }
    }
  }

  // epilogue: total denominator across g-lanes, normalize, write ctx (O^T), fused y
#pragma unroll
  for (int ms = 0; ms < 2; ++ms) {
    float lt = lst[ms];
    lt += __shfl_xor(lt, 16);
    lt += __shfl_xor(lt, 32);
    int l = l0 + wid * 32 + ms * 16 + c;
    if (l < LL) {
      float inv = 1.0f / lt;
      int rb = (b * LL + l) << 7;
      float acc = 0.0f;
#pragma unroll
      for (int n = 0; n < 8; ++n) {
        f4 cv;
#pragma unroll
        for (int i = 0; i < 4; ++i) cv[i] = o[ms][n][i] * inv;
        int fo = n * 16 + (g << 2);
        *(f4*)&ctx[rb + fo] = cv;  // 16B store; 4 g-lanes complete each 64B line
        const f4 fwv = *(const f4*)&fw[(l << 7) + fo];
        acc += cv[0] * fwv[0] + cv[1] * fwv[1] + cv[2] * fwv[2] + cv[3] * fwv[3];
      }
      acc += __shfl_xor(acc, 16);
      acc += __shfl_xor(acc, 32);
      if (g == 0) y[b * LL + l] = acc + fb[l];
    }
  }
}

extern "C" void kernel_launch(void* const* d_in, const int* in_sizes, int n_in,
                              void* d_out, int out_size, void* d_ws, size_t ws_size,
                              hipStream_t stream) {
  const int* docs = (const int*)d_in[0];
  const int* leaf = (const int*)d_in[3];
  const float* embed = (const float*)d_in[4];
  const float* wu = (const float*)d_in[5];
  const float* fw = (const float*)d_in[6];
  const float* fb = (const float*)d_in[7];
  const float* w3 = (const float*)d_in[8];
  const float* b3 = (const float*)d_in[9];
  const float* w5 = (const float*)d_in[10];
  const float* b5 = (const float*)d_in[11];
  const float* w9 = (const float*)d_in[12];
  const float* b9 = (const float*)d_in[13];

  char* ws = (char*)d_ws;
  short* x_bf  = (short*)(ws);              // [B][S][E] bf16
  short* wu_bf = (short*)(ws + 5120000);    // [L][F] bf16
  short* wpack = (short*)(ws + 7403776);    // [17][F][E] bf16
  short* wfp   = (short*)(ws + 7960832);    // [B][S][F] bf16
  short* wfT   = (short*)(ws + 13080832);   // [B][F][S] bf16

  float* y = (float*)d_out;
  float* ctx = (float*)d_out + BB * LL;

  prep_kernel<<<2896, 256, 0, stream>>>(docs, leaf, embed, wu, w3, w5, w9, x_bf, wu_bf, wpack);
  conv_kernel<<<dim3(8, 40), 256, 0, stream>>>(x_bf, wpack, b3, b5, b9, wfp, wfT);
  attn_kernel<<<dim3(8, 70), 256, 0, stream>>>(wu_bf, wfp, wfT, fw, fb, y, ctx);
}

// Round 17
// 208.301 us; speedup vs baseline: 1.2230x; 1.2230x over previous
//
#include <hip/hip_runtime.h>
#include <hip/hip_bf16.h>

#define BB 8
#define SS 2500
#define EE 128
#define FF 128
#define LL 8921

using bf8 = __attribute__((ext_vector_type(8))) short;
using bf4 = __attribute__((ext_vector_type(4))) short;
using f4  = __attribute__((ext_vector_type(4))) float;

__device__ __forceinline__ short f2bf(float f) {
  unsigned u = __builtin_bit_cast(unsigned, f);
  u += 0x7fffu + ((u >> 16) & 1u);
  return (short)(u >> 16);
}

// async global->LDS, 16B per lane; LDS dest is wave-uniform base + lane*16
__device__ __forceinline__ void gll16(const void* g, void* l) {
  __builtin_amdgcn_global_load_lds(
      (const __attribute__((address_space(1))) unsigned int*)g,
      (__attribute__((address_space(3))) unsigned int*)l, 16, 0, 0);
}

// DPP helpers: reduce across the 16-lane group (lane&15) on the VALU pipe (no LDS).
template <int CTRL>
__device__ __forceinline__ float dppmv(float x) {
  int r = __builtin_amdgcn_update_dpp(0, __builtin_bit_cast(int, x), CTRL, 0xF, 0xF, false);
  return __builtin_bit_cast(float, r);
}
__device__ __forceinline__ float rowsum16(float x) {
  x += dppmv<0xB1>(x);    // quad_perm xor1
  x += dppmv<0x4E>(x);    // quad_perm xor2
  x += dppmv<0x124>(x);   // row_ror:4
  x += dppmv<0x128>(x);   // row_ror:8
  return x;
}

// ---------------- prep: embed gather -> bf16, wu -> bf16, conv w repack ----------------
__global__ void prep_kernel(const int* __restrict__ docs, const int* __restrict__ leaf,
                            const float* __restrict__ embed, const float* __restrict__ wu,
                            const float* __restrict__ w3, const float* __restrict__ w5,
                            const float* __restrict__ w9,
                            short* __restrict__ x_bf, short* __restrict__ wu_bf,
                            short* __restrict__ wpack) {
  const int NX = BB * SS * EE / 8;   // 320000
  const int NU = LL * FF / 8;        // 142736
  const int NW = 17 * FF * EE;       // 278528
  int tid = blockIdx.x * 256 + threadIdx.x;
  if (tid < NX) {
    int base = tid * 8;
    int bs = base >> 7, e0 = base & 127;
    int row = docs[bs];
    const float* p = embed + (row << 7) + e0;
    bf8 o;
#pragma unroll
    for (int i = 0; i < 8; ++i) o[i] = f2bf(p[i]);
    *(bf8*)(x_bf + base) = o;
  } else if (tid < NX + NU) {
    int base = (tid - NX) * 8;
    int l = base >> 7, f0 = base & 127;
    int row = leaf[l];
    const float* p = wu + (row << 7) + f0;
    bf8 o;
#pragma unroll
    for (int i = 0; i < 8; ++i) o[i] = f2bf(p[i]);
    *(bf8*)(wu_bf + base) = o;
  } else if (tid < NX + NU + NW) {
    int i = tid - NX - NU;
    int t = i >> 14, fe = i & 16383;
    const float* w; int K, dk;
    if (t < 3)      { w = w3; K = 3; dk = t; }
    else if (t < 8) { w = w5; K = 5; dk = t - 3; }
    else            { w = w9; K = 9; dk = t - 8; }
    wpack[i] = f2bf(w[fe * K + dk]);
  }
}

// ---------------- conv: 3 kernels + tanh + max, MFMA over (e,tap) ----------------
__global__ __launch_bounds__(256, 2) void conv_kernel(
    const short* __restrict__ x_bf, const short* __restrict__ wpack,
    const float* __restrict__ cb3, const float* __restrict__ cb5, const float* __restrict__ cb9,
    short* __restrict__ wf, short* __restrict__ wfT) {
  __shared__ short xt[72][136];   // s rows (halo 4), e cols; 272B stride
  __shared__ short wt[128][136];  // f rows, e cols
  int b = blockIdx.x;             // b fastest -> XCD-local x_bf/wpack
  int s0 = blockIdx.y * 64;
  int tid = threadIdx.x, wid = tid >> 6, lane = tid & 63, g = lane >> 4, c = lane & 15;

  for (int i = tid; i < 72 * 16; i += 256) {
    int r = i >> 4, c8 = (i & 15) << 3, s = s0 + r - 4;
    bf8 v = {0, 0, 0, 0, 0, 0, 0, 0};
    if (s >= 0 && s < SS) v = *(const bf8*)(x_bf + ((b * SS + s) << 7) + c8);
    *(bf8*)&xt[r][c8] = v;
  }

  bf8 wpre[8];
#pragma unroll
  for (int k = 0; k < 8; ++k) {
    int i = tid + (k << 8); int r = i >> 4, c8 = (i & 15) << 3;
    wpre[k] = *(const bf8*)(wpack + (r << 7) + c8);
  }

  float wfm[8][4];
#pragma unroll
  for (int j = 0; j < 8; ++j)
#pragma unroll
    for (int i = 0; i < 4; ++i) wfm[j][i] = -1e30f;

  int tap = 0;
  for (int kid = 0; kid < 3; ++kid) {
    const float* cb = (kid == 0) ? cb3 : (kid == 1) ? cb5 : cb9;
    const int K = (kid == 0) ? 3 : (kid == 1) ? 5 : 9;
    const int pad = K >> 1;
    f4 acc[8];
#pragma unroll
    for (int j = 0; j < 8; ++j) {
      float bvj = cb[j * 16 + c];
      acc[j] = (f4){bvj, bvj, bvj, bvj};
    }
    for (int dk = 0; dk < K; ++dk, ++tap) {
      __syncthreads();
#pragma unroll
      for (int k = 0; k < 8; ++k) {
        int i = tid + (k << 8); int r = i >> 4, c8 = (i & 15) << 3;
        *(bf8*)&wt[r][c8] = wpre[k];
      }
      if (tap < 16) {
#pragma unroll
        for (int k = 0; k < 8; ++k) {
          int i = tid + (k << 8); int r = i >> 4, c8 = (i & 15) << 3;
          wpre[k] = *(const bf8*)(wpack + (tap + 1) * 16384 + (r << 7) + c8);
        }
      }
      __syncthreads();
      int xr = wid * 16 + c + dk - pad + 4;
      __builtin_amdgcn_s_setprio(1);
#pragma unroll
      for (int ks = 0; ks < 4; ++ks) {
        bf8 a = *(const bf8*)&xt[xr][ks * 32 + g * 8];
#pragma unroll
        for (int j = 0; j < 8; ++j) {
          bf8 bb = *(const bf8*)&wt[j * 16 + c][ks * 32 + g * 8];
          acc[j] = __builtin_amdgcn_mfma_f32_16x16x32_bf16(a, bb, acc[j], 0, 0, 0);
        }
      }
      __builtin_amdgcn_s_setprio(0);
    }
#pragma unroll
    for (int j = 0; j < 8; ++j)
#pragma unroll
      for (int i = 0; i < 4; ++i) wfm[j][i] = fmaxf(wfm[j][i], tanhf(acc[j][i]));
  }

  int sb = s0 + wid * 16 + g * 4;
#pragma unroll
  for (int j = 0; j < 8; ++j) {
    int f = j * 16 + c;
#pragma unroll
    for (int i = 0; i < 4; ++i) {
      int s = sb + i;
      if (s < SS) wf[((b * SS + s) << 7) + f] = f2bf(wfm[j][i]);
    }
    int tbase = (b * 128 + f) * SS + sb;
    if (sb + 3 < SS) {
      bf4 pk;
#pragma unroll
      for (int i = 0; i < 4; ++i) pk[i] = f2bf(wfm[j][i]);
      *(bf4*)(wfT + tbase) = pk;
    } else {
#pragma unroll
      for (int i = 0; i < 4; ++i)
        if (sb + i < SS) wfT[tbase + i] = f2bf(wfm[j][i]);
    }
  }
}

// ---------------- flash attention + fused y: Q=wu [L,F], K=V=wf [S,F] ----------------
// PROVEN BEST (R15: total 208.4us, attn 183us): __expf, 2-barrier, j-split QK,
// VGPR 84 spill-free, conflicts 0, 3 blocks/CU, one residency round, fused-y epilogue.
// R16's swapped-QK REGRESSED (-23%): 16x16x16 PV doubles MFMA issue cost (K=16 is NOT
// half the cycles of K=32), 8B vb reads re-alias banks at 128B stride, +18MB spills.
__global__ __launch_bounds__(256, 3) void attn_kernel(
    const short* __restrict__ wu_bf, const short* __restrict__ wf, const short* __restrict__ wfT,
    const float* __restrict__ fw, const float* __restrict__ fb,
    float* __restrict__ y, float* __restrict__ ctx) {
  __shared__ short kt[64 * 128];   // K tile [s][f], swizzled
  __shared__ short vt[128 * 64];   // V^T tile [f][s], swizzled
  __shared__ short pt[128][68];    // P rows [l][s], 136B stride
  int b = blockIdx.x;              // b fastest -> per-XCD K/V residency in L2
  int l0 = blockIdx.y * 128;
  int tid = threadIdx.x, wid = tid >> 6, lane = tid & 63, g = lane >> 4, c = lane & 15;

  // staging source precompute (tile-invariant): call k covers linear chunks (k*4+wid)*64+lane
  int k_row[4], k_off[4], v_off[4];
#pragma unroll
  for (int k = 0; k < 4; ++k) {
    int idx = (k * 4 + wid) * 64 + lane;
    int r = idx >> 4, ck = idx & 15;
    k_row[k] = r;
    k_off[k] = (ck ^ (r & 15)) << 3;             // shorts within wf row
    int rv = idx >> 3, cv = idx & 7;
    v_off[k] = (b * 128 + rv) * SS + ((cv ^ (rv & 7)) << 3);  // shorts into wfT (+s0 per tile)
  }
  const short* wfb = wf + b * SS * 128;

  bf8 q[2][4];
#pragma unroll
  for (int ms = 0; ms < 2; ++ms) {
    int l = l0 + wid * 32 + ms * 16 + c;
    if (l >= LL) l = LL - 1;
#pragma unroll
    for (int ks = 0; ks < 4; ++ks)
      q[ms][ks] = *(const bf8*)(wu_bf + (l << 7) + ks * 32 + g * 8);
  }

  float lst[2][4];
  f4 o[2][8];
#pragma unroll
  for (int ms = 0; ms < 2; ++ms) {
#pragma unroll
    for (int i = 0; i < 4; ++i) lst[ms][i] = 0.0f;
#pragma unroll
    for (int n = 0; n < 8; ++n) o[ms][n] = (f4){0.f, 0.f, 0.f, 0.f};
  }

  for (int t = 0; t < 40; ++t) {
    int s0 = t * 64;
    bool full = (s0 + 64 <= SS);
    __syncthreads();  // all waves done reading tile t-1 (drains lgkm+vm)
    // stage K tile (rows clamped; garbage rows are score-masked)
#pragma unroll
    for (int k = 0; k < 4; ++k) {
      int s = s0 + k_row[k];
      if (s > SS - 1) s = SS - 1;
      gll16(wfb + s * 128 + k_off[k], (char*)kt + (k * 4 + wid) * 1024);
    }
    if (full) {
#pragma unroll
      for (int k = 0; k < 4; ++k)
        gll16(wfT + v_off[k] + s0, (char*)vt + (k * 4 + wid) * 1024);
    } else {
      // tail tile: scalar masked V staging through the same swizzle
      for (int idx = tid; idx < 128 * 64; idx += 256) {
        int r = idx >> 6, sl = idx & 63, so = s0 + sl;
        short v = (so < SS) ? wfT[(b * 128 + r) * SS + so] : (short)0;
        vt[(r << 6) + (((sl >> 3) ^ (r & 7)) << 3) + (sl & 7)] = v;
      }
    }
    __syncthreads();  // barrier drain waits vmcnt(0): tile t staged

    // QK^T + stateless softmax, j-split: kb loaded once per (jh,ks), shared across ms
    float rs[2][4] = {{0.f, 0.f, 0.f, 0.f}, {0.f, 0.f, 0.f, 0.f}};
#pragma unroll
    for (int jh = 0; jh < 2; ++jh) {
      f4 sc[2][2];
#pragma unroll
      for (int ms = 0; ms < 2; ++ms)
#pragma unroll
        for (int jj = 0; jj < 2; ++jj) sc[ms][jj] = (f4){0.f, 0.f, 0.f, 0.f};
      __builtin_amdgcn_s_setprio(1);
#pragma unroll
      for (int ks = 0; ks < 4; ++ks) {
        int xk = (((ks << 2) | g) ^ c) << 3;
        bf8 kb[2];
#pragma unroll
        for (int jj = 0; jj < 2; ++jj)
          kb[jj] = *(const bf8*)&kt[((jh * 2 + jj) * 16 + c) * 128 + xk];
#pragma unroll
        for (int ms = 0; ms < 2; ++ms)
#pragma unroll
          for (int jj = 0; jj < 2; ++jj)
            sc[ms][jj] = __builtin_amdgcn_mfma_f32_16x16x32_bf16(q[ms][ks], kb[jj], sc[ms][jj], 0, 0, 0);
      }
      __builtin_amdgcn_s_setprio(0);
#pragma unroll
      for (int jj = 0; jj < 2; ++jj) {
        int j = jh * 2 + jj;
        int col = j * 16 + c;
        bool masked = (!full) && (s0 + col >= SS);
#pragma unroll
        for (int ms = 0; ms < 2; ++ms) {
          int rbase = wid * 32 + ms * 16 + g * 4;
#pragma unroll
          for (int i = 0; i < 4; ++i) {
            float p = masked ? 0.0f : __expf(sc[ms][jj][i]);  // bounded: exp(|s|<=6.4)
            pt[rbase + i][col] = f2bf(p);  // inline P write (own 32-row strip)
            rs[ms][i] += p;                // unrounded denominator
          }
        }
      }
    }
#pragma unroll
    for (int ms = 0; ms < 2; ++ms)
#pragma unroll
      for (int i = 0; i < 4; ++i) lst[ms][i] += rowsum16(rs[ms][i]);
    asm volatile("s_waitcnt lgkmcnt(0)" ::: "memory");
    __builtin_amdgcn_sched_barrier(0);

    // PV: A = P [l][s] (own strip, b64 pairs), B^T = V^T [f][s] (swizzled b128)
    __builtin_amdgcn_s_setprio(1);
#pragma unroll
    for (int ks = 0; ks < 2; ++ks) {
      bf8 pa[2];
#pragma unroll
      for (int ms = 0; ms < 2; ++ms) {
        const short* pp = &pt[wid * 32 + ms * 16 + c][ks * 32 + g * 8];
        bf4 lo = *(const bf4*)pp; bf4 hi = *(const bf4*)(pp + 4);
        pa[ms] = __builtin_shufflevector(lo, hi, 0, 1, 2, 3, 4, 5, 6, 7);
      }
      int xv = (((ks << 2) | g) ^ (c & 7)) << 3;
#pragma unroll
      for (int n = 0; n < 8; ++n) {
        bf8 vb = *(const bf8*)&vt[(n * 16 + c) * 64 + xv];
#pragma unroll
        for (int ms = 0; ms < 2; ++ms)
          o[ms][n] = __builtin_amdgcn_mfma_f32_16x16x32_bf16(pa[ms], vb, o[ms][n], 0, 0, 0);
      }
    }
    __builtin_amdgcn_s_setprio(0);
  }

  // epilogue: normalize, write ctx, and fused y = ctx . fw + fb
#pragma unroll
  for (int ms = 0; ms < 2; ++ms)
#pragma unroll
    for (int i = 0; i < 4; ++i) {
      int l = l0 + wid * 32 + ms * 16 + g * 4 + i;
      if (l < LL) {
        float inv = 1.0f / lst[ms][i];
        int rb = (b * LL + l) << 7;
        float acc = 0.0f;
#pragma unroll
        for (int n = 0; n < 8; ++n) {
          float cv = o[ms][n][i] * inv;
          ctx[rb + n * 16 + c] = cv;
          acc += cv * fw[(l << 7) + n * 16 + c];
        }
        acc = rowsum16(acc);
        if (c == 0) y[b * LL + l] = acc + fb[l];
      }
    }
}

extern "C" void kernel_launch(void* const* d_in, const int* in_sizes, int n_in,
                              void* d_out, int out_size, void* d_ws, size_t ws_size,
                              hipStream_t stream) {
  const int* docs = (const int*)d_in[0];
  const int* leaf = (const int*)d_in[3];
  const float* embed = (const float*)d_in[4];
  const float* wu = (const float*)d_in[5];
  const float* fw = (const float*)d_in[6];
  const float* fb = (const float*)d_in[7];
  const float* w3 = (const float*)d_in[8];
  const float* b3 = (const float*)d_in[9];
  const float* w5 = (const float*)d_in[10];
  const float* b5 = (const float*)d_in[11];
  const float* w9 = (const float*)d_in[12];
  const float* b9 = (const float*)d_in[13];

  char* ws = (char*)d_ws;
  short* x_bf  = (short*)(ws);              // [B][S][E] bf16
  short* wu_bf = (short*)(ws + 5120000);    // [L][F] bf16
  short* wpack = (short*)(ws + 7403776);    // [17][F][E] bf16
  short* wfp   = (short*)(ws + 7960832);    // [B][S][F] bf16
  short* wfT   = (short*)(ws + 13080832);   // [B][F][S] bf16

  float* y = (float*)d_out;
  float* ctx = (float*)d_out + BB * LL;

  prep_kernel<<<2896, 256, 0, stream>>>(docs, leaf, embed, wu, w3, w5, w9, x_bf, wu_bf, wpack);
  conv_kernel<<<dim3(8, 40), 256, 0, stream>>>(x_bf, wpack, b3, b5, b9, wfp, wfT);
  attn_kernel<<<dim3(8, 70), 256, 0, stream>>>(wu_bf, wfp, wfT, fw, fb, y, ctx);
}